// Round 1
// baseline (2856.790 us; speedup 1.0000x reference)
//
#include <hip/hip_runtime.h>
#include <math.h>

#define NA 100000
#define NB 100000
#define KDIM 256
#define ODIM 256
#define NEDGE 320000
#define NCAT 512   // [proj0 | proj1] concatenated columns

// ---------------------------------------------------------------------------
// Kernel 1: proj = x_B @ [W0 | W1] + [b0 | b1]   (M=100000, K=256, N=512) f32
// 64x64 C-tile, 256 threads, 4x4 microtile, K-tile 16, LDS-staged.
// ---------------------------------------------------------------------------
__global__ __launch_bounds__(256) void proj_gemm(
    const float* __restrict__ xB,
    const float* __restrict__ W0, const float* __restrict__ b0,
    const float* __restrict__ W1, const float* __restrict__ b1,
    float* __restrict__ proj)
{
    __shared__ float As[16][64];   // As[k][m]
    __shared__ float Bs[16][64];   // Bs[k][n]

    const int t  = threadIdx.x;
    const int m0 = blockIdx.y * 64;
    const int n0 = blockIdx.x * 64;          // 0..448, tiles never straddle 256
    const float* Wsrc = (n0 < ODIM) ? W0 : W1;
    const float* bsrc = (n0 < ODIM) ? b0 : b1;
    const int ncol0 = n0 & (ODIM - 1);

    // A-load: thread t loads float4 of row (m0 + t/4), k-offset 4*(t%4)
    const int la_m = t >> 2;
    const int la_k = (t & 3) << 2;
    // B-load: thread t loads float4 of W row (k0 + t/16), col 4*(t%16)
    const int lb_k = t >> 4;
    const int lb_n = (t & 15) << 2;
    // compute microtile position
    const int tx = t & 15, ty = t >> 4;

    float acc[4][4] = {};

    for (int k0 = 0; k0 < KDIM; k0 += 16) {
        const int arow = m0 + la_m;
        float4 av = make_float4(0.f, 0.f, 0.f, 0.f);
        if (arow < NB) av = *(const float4*)&xB[(size_t)arow * KDIM + k0 + la_k];
        As[la_k + 0][la_m] = av.x;
        As[la_k + 1][la_m] = av.y;
        As[la_k + 2][la_m] = av.z;
        As[la_k + 3][la_m] = av.w;

        float4 bv = *(const float4*)&Wsrc[(size_t)(k0 + lb_k) * ODIM + ncol0 + lb_n];
        *((float4*)&Bs[lb_k][lb_n]) = bv;

        __syncthreads();
        #pragma unroll
        for (int k = 0; k < 16; ++k) {
            float4 a4 = *((float4*)&As[k][ty << 2]);
            float4 b4 = *((float4*)&Bs[k][tx << 2]);
            float ar[4] = {a4.x, a4.y, a4.z, a4.w};
            float br[4] = {b4.x, b4.y, b4.z, b4.w};
            #pragma unroll
            for (int i = 0; i < 4; ++i)
                #pragma unroll
                for (int j = 0; j < 4; ++j)
                    acc[i][j] = fmaf(ar[i], br[j], acc[i][j]);
        }
        __syncthreads();
    }

    float4 bias = *(const float4*)&bsrc[ncol0 + (tx << 2)];
    #pragma unroll
    for (int i = 0; i < 4; ++i) {
        const int row = m0 + (ty << 2) + i;
        if (row < NB) {
            float4 o;
            o.x = acc[i][0] + bias.x;
            o.y = acc[i][1] + bias.y;
            o.z = acc[i][2] + bias.z;
            o.w = acc[i][3] + bias.w;
            *(float4*)&proj[(size_t)row * NCAT + n0 + (tx << 2)] = o;
        }
    }
}

// ---------------------------------------------------------------------------
// Kernel 2: per-edge gather + scatter-add.  One wave (64 lanes) per edge,
// 4 floats per lane (float4 gather, 4 scalar f32 atomics). Both paths in one
// grid: wave id < NEDGE -> path0, else path1.
// agg0 = out[0 .. NA*256), agg1 = out[NA*256 .. 2*NA*256)   (pre-zeroed)
// cnt  = [2*NA] floats (pre-zeroed)
// ---------------------------------------------------------------------------
__global__ __launch_bounds__(256) void scatter_agg(
    const int* __restrict__ ei0, const int* __restrict__ ei1,
    const float* __restrict__ proj,
    float* __restrict__ agg, float* __restrict__ cnt)
{
    const int gw   = (int)((blockIdx.x * (size_t)blockDim.x + threadIdx.x) >> 6);
    const int lane = threadIdx.x & 63;
    if (gw >= 2 * NEDGE) return;
    const int p = (gw >= NEDGE) ? 1 : 0;
    const int j = p ? (gw - NEDGE) : gw;
    const int* ei = p ? ei1 : ei0;
    const int src = ei[j];           // row 0 of edge_index
    const int dst = ei[NEDGE + j];   // row 1 of edge_index

    float4 v = *(const float4*)&proj[(size_t)src * NCAT + p * ODIM + (lane << 2)];
    float* arow = agg + (size_t)p * NA * ODIM + (size_t)dst * ODIM + (lane << 2);
    atomicAdd(arow + 0, v.x);
    atomicAdd(arow + 1, v.y);
    atomicAdd(arow + 2, v.z);
    atomicAdd(arow + 3, v.w);
    if (lane == 0) atomicAdd(&cnt[p * NA + dst], 1.0f);
}

// ---------------------------------------------------------------------------
// Kernel 3: finalize.  One wave per destination node:
//   mean0/mean1 -> tanh dot sem -> softmax(2) -> fuse -> relu -> LN -> out_A
// Reads agg from d_out halves in-place; zeroes the out_B half afterwards.
// ---------------------------------------------------------------------------
__global__ __launch_bounds__(256) void finalize(
    float* __restrict__ out, const float* __restrict__ cnt,
    const float* __restrict__ sem, const float* __restrict__ gamma,
    const float* __restrict__ beta)
{
    const int row  = (int)((blockIdx.x * (size_t)blockDim.x + threadIdx.x) >> 6);
    const int lane = threadIdx.x & 63;
    if (row >= NA) return;
    const int d = lane << 2;

    float4 a0 = *(float4*)&out[(size_t)row * ODIM + d];
    float4 a1 = *(float4*)&out[(size_t)(NA + row) * ODIM + d];
    const float inv0 = 1.0f / fmaxf(cnt[row], 1.0f);
    const float inv1 = 1.0f / fmaxf(cnt[NA + row], 1.0f);
    float m0x = a0.x * inv0, m0y = a0.y * inv0, m0z = a0.z * inv0, m0w = a0.w * inv0;
    float m1x = a1.x * inv1, m1y = a1.y * inv1, m1z = a1.z * inv1, m1w = a1.w * inv1;

    float4 sm = *(const float4*)&sem[d];
    float s0 = tanhf(m0x) * sm.x + tanhf(m0y) * sm.y + tanhf(m0z) * sm.z + tanhf(m0w) * sm.w;
    float s1 = tanhf(m1x) * sm.x + tanhf(m1y) * sm.y + tanhf(m1z) * sm.z + tanhf(m1w) * sm.w;
    #pragma unroll
    for (int off = 32; off > 0; off >>= 1) {
        s0 += __shfl_xor(s0, off);
        s1 += __shfl_xor(s1, off);
    }
    const float mx = fmaxf(s0, s1);
    const float e0 = __expf(s0 - mx), e1 = __expf(s1 - mx);
    const float w0 = e0 / (e0 + e1), w1 = e1 / (e0 + e1);

    float fx = fmaxf(w0 * m0x + w1 * m1x, 0.f);
    float fy = fmaxf(w0 * m0y + w1 * m1y, 0.f);
    float fz = fmaxf(w0 * m0z + w1 * m1z, 0.f);
    float fw = fmaxf(w0 * m0w + w1 * m1w, 0.f);

    float sum = fx + fy + fz + fw;
    float sq  = fx * fx + fy * fy + fz * fz + fw * fw;
    #pragma unroll
    for (int off = 32; off > 0; off >>= 1) {
        sum += __shfl_xor(sum, off);
        sq  += __shfl_xor(sq, off);
    }
    const float mu  = sum * (1.0f / ODIM);
    const float var = sq * (1.0f / ODIM) - mu * mu;
    const float rinv = rsqrtf(var + 1e-5f);

    float4 g  = *(const float4*)&gamma[d];
    float4 be = *(const float4*)&beta[d];
    float4 o;
    o.x = (fx - mu) * rinv * g.x + be.x;
    o.y = (fy - mu) * rinv * g.y + be.y;
    o.z = (fz - mu) * rinv * g.z + be.z;
    o.w = (fw - mu) * rinv * g.w + be.w;
    *(float4*)&out[(size_t)row * ODIM + d] = o;
    // out_B row (second half) must be zeros; we already consumed agg1 above.
    *(float4*)&out[(size_t)(NA + row) * ODIM + d] = make_float4(0.f, 0.f, 0.f, 0.f);
}

// ---------------------------------------------------------------------------
extern "C" void kernel_launch(void* const* d_in, const int* in_sizes, int n_in,
                              void* d_out, int out_size, void* d_ws, size_t ws_size,
                              hipStream_t stream)
{
    // setup_inputs order:
    // 0 x_A, 1 x_B, 2 edge_index0, 3 edge_index1, 4 W0, 5 b0, 6 W1, 7 b1,
    // 8 sem_vec, 9 gamma, 10 beta
    const float* xB   = (const float*)d_in[1];
    const int*   ei0  = (const int*)d_in[2];
    const int*   ei1  = (const int*)d_in[3];
    const float* W0   = (const float*)d_in[4];
    const float* b0   = (const float*)d_in[5];
    const float* W1   = (const float*)d_in[6];
    const float* b1   = (const float*)d_in[7];
    const float* sem  = (const float*)d_in[8];
    const float* gam  = (const float*)d_in[9];
    const float* bet  = (const float*)d_in[10];

    float* out = (float*)d_out;

    const size_t proj_elems = (size_t)NB * NCAT;          // 51.2M floats
    float* proj = (float*)d_ws;
    float* cnt  = (float*)((char*)d_ws + proj_elems * sizeof(float));

    // zero agg accumulators (both halves of d_out) and counts
    hipMemsetAsync(d_out, 0, (size_t)2 * NA * ODIM * sizeof(float), stream);
    hipMemsetAsync(cnt, 0, (size_t)2 * NA * sizeof(float), stream);

    // 1) projection GEMM
    dim3 ggrid(NCAT / 64, (NB + 63) / 64);
    proj_gemm<<<ggrid, 256, 0, stream>>>(xB, W0, b0, W1, b1, proj);

    // 2) edge scatter (both paths): 2*NEDGE waves, 4 waves/block
    const int nwaves = 2 * NEDGE;
    scatter_agg<<<(nwaves + 3) / 4, 256, 0, stream>>>(ei0, ei1, proj, out, cnt);

    // 3) finalize: NA waves, 4 waves/block
    finalize<<<(NA + 3) / 4, 256, 0, stream>>>(out, cnt, sem, gam, bet);
}

// Round 2
// 839.967 us; speedup vs baseline: 3.4011x; 3.4011x over previous
//
#include <hip/hip_runtime.h>
#include <math.h>

#define NA 100000
#define NB 100000
#define KDIM 256
#define ODIM 256
#define NEDGE 320000
#define NCAT 512            // [proj0 | proj1] concatenated columns
#define NBUCK (2 * NA)      // path-major destination buckets
#define NPART 782           // ceil(NBUCK / 256)

typedef unsigned int u32;

// ---------------------------------------------------------------------------
// Kernel 1: proj = x_B @ [W0 | W1] + [b0 | b1]   (M=100000, K=256, N=512) f32
// 64x64 C-tile, 256 threads, 4x4 microtile, K-tile 16, LDS-staged.
// ---------------------------------------------------------------------------
__global__ __launch_bounds__(256) void proj_gemm(
    const float* __restrict__ xB,
    const float* __restrict__ W0, const float* __restrict__ b0,
    const float* __restrict__ W1, const float* __restrict__ b1,
    float* __restrict__ proj)
{
    __shared__ float As[16][64];   // As[k][m]
    __shared__ float Bs[16][64];   // Bs[k][n]

    const int t  = threadIdx.x;
    const int m0 = blockIdx.y * 64;
    const int n0 = blockIdx.x * 64;          // 0..448, tiles never straddle 256
    const float* Wsrc = (n0 < ODIM) ? W0 : W1;
    const float* bsrc = (n0 < ODIM) ? b0 : b1;
    const int ncol0 = n0 & (ODIM - 1);

    const int la_m = t >> 2;
    const int la_k = (t & 3) << 2;
    const int lb_k = t >> 4;
    const int lb_n = (t & 15) << 2;
    const int tx = t & 15, ty = t >> 4;

    float acc[4][4] = {};

    for (int k0 = 0; k0 < KDIM; k0 += 16) {
        const int arow = m0 + la_m;
        float4 av = make_float4(0.f, 0.f, 0.f, 0.f);
        if (arow < NB) av = *(const float4*)&xB[(size_t)arow * KDIM + k0 + la_k];
        As[la_k + 0][la_m] = av.x;
        As[la_k + 1][la_m] = av.y;
        As[la_k + 2][la_m] = av.z;
        As[la_k + 3][la_m] = av.w;

        float4 bv = *(const float4*)&Wsrc[(size_t)(k0 + lb_k) * ODIM + ncol0 + lb_n];
        *((float4*)&Bs[lb_k][lb_n]) = bv;

        __syncthreads();
        #pragma unroll
        for (int k = 0; k < 16; ++k) {
            float4 a4 = *((float4*)&As[k][ty << 2]);
            float4 b4 = *((float4*)&Bs[k][tx << 2]);
            float ar[4] = {a4.x, a4.y, a4.z, a4.w};
            float br[4] = {b4.x, b4.y, b4.z, b4.w};
            #pragma unroll
            for (int i = 0; i < 4; ++i)
                #pragma unroll
                for (int j = 0; j < 4; ++j)
                    acc[i][j] = fmaf(ar[i], br[j], acc[i][j]);
        }
        __syncthreads();
    }

    float4 bias = *(const float4*)&bsrc[ncol0 + (tx << 2)];
    #pragma unroll
    for (int i = 0; i < 4; ++i) {
        const int row = m0 + (ty << 2) + i;
        if (row < NB) {
            float4 o;
            o.x = acc[i][0] + bias.x;
            o.y = acc[i][1] + bias.y;
            o.z = acc[i][2] + bias.z;
            o.w = acc[i][3] + bias.w;
            *(float4*)&proj[(size_t)row * NCAT + n0 + (tx << 2)] = o;
        }
    }
}

// ---------------------------------------------------------------------------
// CSR build: count -> block scan -> partial scan -> add+cursor -> fill
// Buckets are path-major: bucket(p, dst) = p*NA + dst.
// ---------------------------------------------------------------------------
__global__ __launch_bounds__(256) void csr_count(
    const int* __restrict__ ei0, const int* __restrict__ ei1,
    u32* __restrict__ cnt)
{
    const int gid = blockIdx.x * 256 + threadIdx.x;
    if (gid >= 2 * NEDGE) return;
    const int p = (gid >= NEDGE) ? 1 : 0;
    const int j = gid - p * NEDGE;
    const int* ei = p ? ei1 : ei0;
    const int dst = ei[NEDGE + j];
    atomicAdd(&cnt[p * NA + dst], 1u);
}

// per-256-block exclusive scan; block totals to parts[]
__global__ __launch_bounds__(256) void scan1(
    const u32* __restrict__ cnt, u32* __restrict__ offs, u32* __restrict__ parts)
{
    __shared__ u32 s[256];
    const int t = threadIdx.x;
    const int idx = blockIdx.x * 256 + t;
    u32 v = (idx < NBUCK) ? cnt[idx] : 0u;
    s[t] = v;
    __syncthreads();
    #pragma unroll
    for (int off = 1; off < 256; off <<= 1) {
        u32 u = (t >= off) ? s[t - off] : 0u;
        __syncthreads();
        s[t] += u;
        __syncthreads();
    }
    if (idx < NBUCK) offs[idx] = s[t] - v;        // exclusive
    if (t == 255) parts[blockIdx.x] = s[255];     // block total
}

// single-block exclusive scan of NPART partials (padded to 1024)
__global__ __launch_bounds__(1024) void scan2(u32* __restrict__ parts)
{
    __shared__ u32 s[1024];
    const int t = threadIdx.x;
    u32 v = (t < NPART) ? parts[t] : 0u;
    s[t] = v;
    __syncthreads();
    #pragma unroll
    for (int off = 1; off < 1024; off <<= 1) {
        u32 u = (t >= off) ? s[t - off] : 0u;
        __syncthreads();
        s[t] += u;
        __syncthreads();
    }
    if (t < NPART) parts[t] = s[t] - v;           // exclusive
}

__global__ __launch_bounds__(256) void scan3(
    u32* __restrict__ offs, const u32* __restrict__ parts, u32* __restrict__ cursor)
{
    const int idx = blockIdx.x * 256 + threadIdx.x;
    if (idx < NBUCK) {
        u32 o = offs[idx] + parts[blockIdx.x];
        offs[idx] = o;
        cursor[idx] = o;
    }
    if (idx == 0) offs[NBUCK] = 2 * NEDGE;
}

__global__ __launch_bounds__(256) void csr_fill(
    const int* __restrict__ ei0, const int* __restrict__ ei1,
    u32* __restrict__ cursor, int* __restrict__ elist)
{
    const int gid = blockIdx.x * 256 + threadIdx.x;
    if (gid >= 2 * NEDGE) return;
    const int p = (gid >= NEDGE) ? 1 : 0;
    const int j = gid - p * NEDGE;
    const int* ei = p ? ei1 : ei0;
    const int src = ei[j];
    const int dst = ei[NEDGE + j];
    const u32 pos = atomicAdd(&cursor[p * NA + dst], 1u);
    elist[pos] = src;
}

// ---------------------------------------------------------------------------
// Fused gather + mean + semantic-softmax + relu + LayerNorm.
// One wave per destination node; accumulates both paths in registers.
// ---------------------------------------------------------------------------
__global__ __launch_bounds__(256) void gather_finalize(
    const float* __restrict__ proj,
    const u32* __restrict__ offs, const int* __restrict__ elist,
    float* __restrict__ out,
    const float* __restrict__ sem, const float* __restrict__ gamma,
    const float* __restrict__ beta)
{
    const int row  = (int)((blockIdx.x * (size_t)blockDim.x + threadIdx.x) >> 6);
    const int lane = threadIdx.x & 63;
    if (row >= NA) return;
    const int d = lane << 2;

    const u32 b0s = offs[row],        b0e = offs[row + 1];
    const u32 b1s = offs[NA + row],   b1e = offs[NA + row + 1];

    float4 a0 = make_float4(0.f, 0.f, 0.f, 0.f);
    float4 a1 = make_float4(0.f, 0.f, 0.f, 0.f);

    for (u32 j = b0s; j < b0e; ++j) {
        const int src = elist[j];
        float4 v = *(const float4*)&proj[(size_t)src * NCAT + d];
        a0.x += v.x; a0.y += v.y; a0.z += v.z; a0.w += v.w;
    }
    for (u32 j = b1s; j < b1e; ++j) {
        const int src = elist[j];
        float4 v = *(const float4*)&proj[(size_t)src * NCAT + ODIM + d];
        a1.x += v.x; a1.y += v.y; a1.z += v.z; a1.w += v.w;
    }

    const float inv0 = 1.0f / fmaxf((float)(b0e - b0s), 1.0f);
    const float inv1 = 1.0f / fmaxf((float)(b1e - b1s), 1.0f);
    float m0x = a0.x * inv0, m0y = a0.y * inv0, m0z = a0.z * inv0, m0w = a0.w * inv0;
    float m1x = a1.x * inv1, m1y = a1.y * inv1, m1z = a1.z * inv1, m1w = a1.w * inv1;

    float4 sm = *(const float4*)&sem[d];
    float s0 = tanhf(m0x) * sm.x + tanhf(m0y) * sm.y + tanhf(m0z) * sm.z + tanhf(m0w) * sm.w;
    float s1 = tanhf(m1x) * sm.x + tanhf(m1y) * sm.y + tanhf(m1z) * sm.z + tanhf(m1w) * sm.w;
    #pragma unroll
    for (int off = 32; off > 0; off >>= 1) {
        s0 += __shfl_xor(s0, off);
        s1 += __shfl_xor(s1, off);
    }
    const float mx = fmaxf(s0, s1);
    const float e0 = __expf(s0 - mx), e1 = __expf(s1 - mx);
    const float w0 = e0 / (e0 + e1), w1 = e1 / (e0 + e1);

    float fx = fmaxf(w0 * m0x + w1 * m1x, 0.f);
    float fy = fmaxf(w0 * m0y + w1 * m1y, 0.f);
    float fz = fmaxf(w0 * m0z + w1 * m1z, 0.f);
    float fw = fmaxf(w0 * m0w + w1 * m1w, 0.f);

    float sum = fx + fy + fz + fw;
    float sq  = fx * fx + fy * fy + fz * fz + fw * fw;
    #pragma unroll
    for (int off = 32; off > 0; off >>= 1) {
        sum += __shfl_xor(sum, off);
        sq  += __shfl_xor(sq, off);
    }
    const float mu  = sum * (1.0f / ODIM);
    const float var = sq * (1.0f / ODIM) - mu * mu;
    const float rinv = rsqrtf(var + 1e-5f);

    float4 g  = *(const float4*)&gamma[d];
    float4 be = *(const float4*)&beta[d];
    float4 o;
    o.x = (fx - mu) * rinv * g.x + be.x;
    o.y = (fy - mu) * rinv * g.y + be.y;
    o.z = (fz - mu) * rinv * g.z + be.z;
    o.w = (fw - mu) * rinv * g.w + be.w;
    *(float4*)&out[(size_t)row * ODIM + d] = o;
}

// ---------------------------------------------------------------------------
extern "C" void kernel_launch(void* const* d_in, const int* in_sizes, int n_in,
                              void* d_out, int out_size, void* d_ws, size_t ws_size,
                              hipStream_t stream)
{
    const float* xB   = (const float*)d_in[1];
    const int*   ei0  = (const int*)d_in[2];
    const int*   ei1  = (const int*)d_in[3];
    const float* W0   = (const float*)d_in[4];
    const float* b0   = (const float*)d_in[5];
    const float* W1   = (const float*)d_in[6];
    const float* b1   = (const float*)d_in[7];
    const float* sem  = (const float*)d_in[8];
    const float* gam  = (const float*)d_in[9];
    const float* bet  = (const float*)d_in[10];

    float* out = (float*)d_out;

    // proj in workspace (204.8 MB)
    float* proj = (float*)d_ws;

    // CSR scratch lives in the out_B half of d_out (zeroed at the end).
    // Needs ~5 MB of the 102.4 MB available.
    u32* scratch = (u32*)(out + (size_t)NA * ODIM);
    u32* cnt    = scratch;                 // NBUCK
    u32* offs   = cnt    + 200064;         // NBUCK + 1
    u32* parts  = offs   + 200128;         // 1024
    u32* cursor = parts  + 1024;           // NBUCK
    int* elist  = (int*)(cursor + 200064); // 2*NEDGE

    // 1) projection GEMM
    dim3 ggrid(NCAT / 64, (NB + 63) / 64);
    proj_gemm<<<ggrid, 256, 0, stream>>>(xB, W0, b0, W1, b1, proj);

    // 2) CSR build
    hipMemsetAsync(cnt, 0, (size_t)NBUCK * sizeof(u32), stream);
    const int egrid = (2 * NEDGE + 255) / 256;
    csr_count<<<egrid, 256, 0, stream>>>(ei0, ei1, cnt);
    scan1<<<NPART, 256, 0, stream>>>(cnt, offs, parts);
    scan2<<<1, 1024, 0, stream>>>(parts);
    scan3<<<NPART, 256, 0, stream>>>(offs, parts, cursor);
    csr_fill<<<egrid, 256, 0, stream>>>(ei0, ei1, cursor, elist);

    // 3) fused gather + epilogue: NA waves, 4 waves/block
    gather_finalize<<<(NA + 3) / 4, 256, 0, stream>>>(proj, offs, elist, out,
                                                      sem, gam, bet);

    // 4) out_B half must be zeros (also wipes CSR scratch)
    hipMemsetAsync(out + (size_t)NA * ODIM, 0,
                   (size_t)NA * ODIM * sizeof(float), stream);
}

// Round 4
// 664.462 us; speedup vs baseline: 4.2994x; 1.2641x over previous
//
#include <hip/hip_runtime.h>
#include <math.h>

#define NA 100000
#define NB 100000
#define KDIM 256
#define ODIM 256
#define NEDGE 320000
#define NCAT 512            // [proj0 | proj1] concatenated columns (f32)
#define NBUCK (2 * NA)      // path-major destination buckets
#define NPART 782           // ceil(NBUCK / 256)

typedef unsigned int u32;
typedef __bf16 bf16x8 __attribute__((ext_vector_type(8)));
typedef float  f32x4  __attribute__((ext_vector_type(4)));

// ---------------------------------------------------------------------------
// Build split-bf16 Wt: Wth/Wtl[n][k] = hi/lo of [W0|W1]^T, plus bcat biases.
// ---------------------------------------------------------------------------
__global__ __launch_bounds__(256) void convert_w(
    const float* __restrict__ W0, const float* __restrict__ b0,
    const float* __restrict__ W1, const float* __restrict__ b1,
    __bf16* __restrict__ Wth, __bf16* __restrict__ Wtl,
    float* __restrict__ bcat)
{
    const int t = blockIdx.x * 256 + threadIdx.x;      // 512*32 threads
    if (t >= 512 * 32) return;
    const int n  = t >> 5;
    const int kb = (t & 31) * 8;
    const float* src = (n < ODIM) ? (W0 + n) : (W1 + (n - ODIM));
    bf16x8 vh, vl;
    #pragma unroll
    for (int j = 0; j < 8; ++j) {
        float w = src[(size_t)(kb + j) * ODIM];
        __bf16 h = (__bf16)w;
        vh[j] = h;
        vl[j] = (__bf16)(w - (float)h);
    }
    *(bf16x8*)&Wth[(size_t)n * KDIM + kb] = vh;
    *(bf16x8*)&Wtl[(size_t)n * KDIM + kb] = vl;
    if ((t & 31) == 0) bcat[n] = (n < ODIM) ? b0[n] : b1[n - ODIM];
}

// ---------------------------------------------------------------------------
// Split-bf16 MFMA GEMM: projf = f32( x @ [W0|W1] + bcat ),  M=100000 N=512 K=256
//   x = xh + xl (split in-register from f32 during staging)
//   proj ≈ xh*Wh + xh*Wl + xl*Wh      (lo*lo dropped, ~2^-18 rel)
// 128x128 tile, 4 waves (2x2 of 64x64), 16x16x32 bf16 MFMA, BK=32.
// LDS fragment-order slots: slot = tile16*64 + lane, 16 B/slot.
// ---------------------------------------------------------------------------
__global__ __launch_bounds__(256) void proj_gemm(
    const float* __restrict__ x,
    const __bf16* __restrict__ Wth, const __bf16* __restrict__ Wtl,
    const float* __restrict__ bcat, float* __restrict__ projf)
{
    __shared__ __align__(16) char smem[32768];
    bf16x8* Ah = (bf16x8*)smem;               // 512 slots (8 KB)
    bf16x8* Al = (bf16x8*)(smem + 8192);
    bf16x8* Bh = (bf16x8*)(smem + 16384);
    bf16x8* Bl = (bf16x8*)(smem + 24576);

    const int t    = threadIdx.x;
    const int w    = t >> 6;
    const int lane = t & 63;
    const int m0   = blockIdx.y * 128;
    const int n0   = blockIdx.x * 128;
    const int wm   = w & 1, wn = w >> 1;

    const int srow = w * 16 + (lane & 15);       // row within 128-tile, pass0
    const int kc   = (lane >> 4) * 8;            // k offset within BK tile
    const int arow0 = min(m0 + srow,      NB - 1);
    const int arow1 = min(m0 + srow + 64, NB - 1);
    const int brow0 = n0 + srow;                 // Wt row (n), < 512 always
    const int brow1 = brow0 + 64;

    f32x4 acc[4][4] = {};

    for (int k0 = 0; k0 < KDIM; k0 += 32) {
        // A: load 8 f32 per row-chunk, split to hi/lo bf16
        const float4* pa0 = (const float4*)&x[(size_t)arow0 * KDIM + k0 + kc];
        const float4* pa1 = (const float4*)&x[(size_t)arow1 * KDIM + k0 + kc];
        float4 a00 = pa0[0], a01 = pa0[1];
        float4 a10 = pa1[0], a11 = pa1[1];
        bf16x8 ah0, al0, ah1, al1;
        {
            float f0[8] = {a00.x, a00.y, a00.z, a00.w, a01.x, a01.y, a01.z, a01.w};
            float f1[8] = {a10.x, a10.y, a10.z, a10.w, a11.x, a11.y, a11.z, a11.w};
            #pragma unroll
            for (int j = 0; j < 8; ++j) {
                __bf16 h0 = (__bf16)f0[j];
                ah0[j] = h0; al0[j] = (__bf16)(f0[j] - (float)h0);
                __bf16 h1 = (__bf16)f1[j];
                ah1[j] = h1; al1[j] = (__bf16)(f1[j] - (float)h1);
            }
        }
        bf16x8 gh0 = *(const bf16x8*)&Wth[(size_t)brow0 * KDIM + k0 + kc];
        bf16x8 gh1 = *(const bf16x8*)&Wth[(size_t)brow1 * KDIM + k0 + kc];
        bf16x8 gl0 = *(const bf16x8*)&Wtl[(size_t)brow0 * KDIM + k0 + kc];
        bf16x8 gl1 = *(const bf16x8*)&Wtl[(size_t)brow1 * KDIM + k0 + kc];

        __syncthreads();                 // previous iter's frag reads done
        Ah[t] = ah0;  Ah[t + 256] = ah1;
        Al[t] = al0;  Al[t + 256] = al1;
        Bh[t] = gh0;  Bh[t + 256] = gh1;
        Bl[t] = gl0;  Bl[t + 256] = gl1;
        __syncthreads();

        bf16x8 afh[4], afl[4], bgh[4], bgl[4];
        #pragma unroll
        for (int i = 0; i < 4; ++i) {
            afh[i] = Ah[(wm * 4 + i) * 64 + lane];
            afl[i] = Al[(wm * 4 + i) * 64 + lane];
        }
        #pragma unroll
        for (int j = 0; j < 4; ++j) {
            bgh[j] = Bh[(wn * 4 + j) * 64 + lane];
            bgl[j] = Bl[(wn * 4 + j) * 64 + lane];
        }
        #pragma unroll
        for (int i = 0; i < 4; ++i)
            #pragma unroll
            for (int j = 0; j < 4; ++j) {
                acc[i][j] = __builtin_amdgcn_mfma_f32_16x16x32_bf16(
                    afl[i], bgh[j], acc[i][j], 0, 0, 0);
                acc[i][j] = __builtin_amdgcn_mfma_f32_16x16x32_bf16(
                    afh[i], bgl[j], acc[i][j], 0, 0, 0);
                acc[i][j] = __builtin_amdgcn_mfma_f32_16x16x32_bf16(
                    afh[i], bgh[j], acc[i][j], 0, 0, 0);
            }
    }

    // bias per lane per nt
    float bias[4];
    #pragma unroll
    for (int j = 0; j < 4; ++j)
        bias[j] = bcat[n0 + wn * 64 + j * 16 + (lane & 15)];

    __syncthreads();                     // all MFMA LDS reads done
    // epilogue: per-wave [16][68] f32 region, LDS roundtrip to coalesce
    float* ep = (float*)(smem + w * 4352);
    const int quad = lane >> 4, c16 = lane & 15;
    const int lr = lane >> 2, lc = (lane & 3) * 16;

    for (int i = 0; i < 4; ++i) {        // mt band
        #pragma unroll
        for (int j = 0; j < 4; ++j)
            #pragma unroll
            for (int r = 0; r < 4; ++r)
                ep[(quad * 4 + r) * 68 + j * 16 + c16] = acc[i][j][r] + bias[j];
        __syncthreads();
        f32x4 v0 = *(f32x4*)&ep[lr * 68 + lc + 0];
        f32x4 v1 = *(f32x4*)&ep[lr * 68 + lc + 4];
        f32x4 v2 = *(f32x4*)&ep[lr * 68 + lc + 8];
        f32x4 v3 = *(f32x4*)&ep[lr * 68 + lc + 12];
        __syncthreads();
        const int rg = m0 + wm * 64 + i * 16 + lr;
        if (rg < NB) {
            float* dst = &projf[(size_t)rg * NCAT + n0 + wn * 64 + lc];
            *(f32x4*)(dst + 0)  = v0;
            *(f32x4*)(dst + 4)  = v1;
            *(f32x4*)(dst + 8)  = v2;
            *(f32x4*)(dst + 12) = v3;
        }
    }
}

// ---------------------------------------------------------------------------
// CSR build: count -> block scan -> partial scan -> add+cursor -> fill
// ---------------------------------------------------------------------------
__global__ __launch_bounds__(256) void csr_count(
    const int* __restrict__ ei0, const int* __restrict__ ei1,
    u32* __restrict__ cnt)
{
    const int gid = blockIdx.x * 256 + threadIdx.x;
    if (gid >= 2 * NEDGE) return;
    const int p = (gid >= NEDGE) ? 1 : 0;
    const int j = gid - p * NEDGE;
    const int* ei = p ? ei1 : ei0;
    const int dst = ei[NEDGE + j];
    atomicAdd(&cnt[p * NA + dst], 1u);
}

__global__ __launch_bounds__(256) void scan1(
    const u32* __restrict__ cnt, u32* __restrict__ offs, u32* __restrict__ parts)
{
    __shared__ u32 s[256];
    const int t = threadIdx.x;
    const int idx = blockIdx.x * 256 + t;
    u32 v = (idx < NBUCK) ? cnt[idx] : 0u;
    s[t] = v;
    __syncthreads();
    #pragma unroll
    for (int off = 1; off < 256; off <<= 1) {
        u32 u = (t >= off) ? s[t - off] : 0u;
        __syncthreads();
        s[t] += u;
        __syncthreads();
    }
    if (idx < NBUCK) offs[idx] = s[t] - v;
    if (t == 255) parts[blockIdx.x] = s[255];
}

__global__ __launch_bounds__(1024) void scan2(u32* __restrict__ parts)
{
    __shared__ u32 s[1024];
    const int t = threadIdx.x;
    u32 v = (t < NPART) ? parts[t] : 0u;
    s[t] = v;
    __syncthreads();
    #pragma unroll
    for (int off = 1; off < 1024; off <<= 1) {
        u32 u = (t >= off) ? s[t - off] : 0u;
        __syncthreads();
        s[t] += u;
        __syncthreads();
    }
    if (t < NPART) parts[t] = s[t] - v;
}

__global__ __launch_bounds__(256) void scan3(
    u32* __restrict__ offs, const u32* __restrict__ parts, u32* __restrict__ cursor)
{
    const int idx = blockIdx.x * 256 + threadIdx.x;
    if (idx < NBUCK) {
        u32 o = offs[idx] + parts[blockIdx.x];
        offs[idx] = o;
        cursor[idx] = o;
    }
    if (idx == 0) offs[NBUCK] = 2 * NEDGE;
}

__global__ __launch_bounds__(256) void csr_fill(
    const int* __restrict__ ei0, const int* __restrict__ ei1,
    u32* __restrict__ cursor, int* __restrict__ elist)
{
    const int gid = blockIdx.x * 256 + threadIdx.x;
    if (gid >= 2 * NEDGE) return;
    const int p = (gid >= NEDGE) ? 1 : 0;
    const int j = gid - p * NEDGE;
    const int* ei = p ? ei1 : ei0;
    const int src = ei[j];
    const int dst = ei[NEDGE + j];
    const u32 pos = atomicAdd(&cursor[p * NA + dst], 1u);
    elist[pos] = src;
}

// ---------------------------------------------------------------------------
// Fused gather + mean + semantic-softmax + relu + LayerNorm.  f32 proj.
// One wave per destination node; lanes 0-31 = path0, lanes 32-63 = path1,
// each lane owns 8 f32 columns (two float4 chunks of the proj row).
// ---------------------------------------------------------------------------
__global__ __launch_bounds__(256) void gather_finalize(
    const float* __restrict__ projf,
    const u32* __restrict__ offs, const int* __restrict__ elist,
    float* __restrict__ out,
    const float* __restrict__ sem, const float* __restrict__ gamma,
    const float* __restrict__ beta)
{
    const int row  = (int)((blockIdx.x * (size_t)blockDim.x + threadIdx.x) >> 6);
    const int lane = threadIdx.x & 63;
    if (row >= NA) return;
    const int p  = lane >> 5;        // path
    const int li = lane & 31;        // lane within half
    const int c  = li * 8;           // first of 8 owned columns

    const u32 bs = offs[p * NA + row];
    const u32 be = offs[p * NA + row + 1];

    float a[8] = {};
    for (u32 j = bs; j < be; ++j) {
        const int src = elist[j];
        const float4* rp = (const float4*)&projf[(size_t)src * NCAT + p * ODIM + c];
        float4 v0 = rp[0], v1 = rp[1];
        a[0] += v0.x; a[1] += v0.y; a[2] += v0.z; a[3] += v0.w;
        a[4] += v1.x; a[5] += v1.y; a[6] += v1.z; a[7] += v1.w;
    }
    const float inv = 1.0f / fmaxf((float)(be - bs), 1.0f);
    float m[8];
    #pragma unroll
    for (int i = 0; i < 8; ++i) m[i] = a[i] * inv;

    // semantic score for own path
    float4 s0 = *(const float4*)&sem[c];
    float4 s1 = *(const float4*)&sem[c + 4];
    float sv[8] = {s0.x, s0.y, s0.z, s0.w, s1.x, s1.y, s1.z, s1.w};
    float s = 0.f;
    #pragma unroll
    for (int i = 0; i < 8; ++i) s += tanhf(m[i]) * sv[i];
    #pragma unroll
    for (int off = 1; off <= 16; off <<= 1) s += __shfl_xor(s, off);
    const float so = __shfl_xor(s, 32);
    const float mx = fmaxf(s, so);
    const float e  = __expf(s - mx), eo = __expf(so - mx);
    const float wown = e / (e + eo), woth = eo / (e + eo);

    float fused[8];
    float sum = 0.f, sq = 0.f;
    #pragma unroll
    for (int i = 0; i < 8; ++i) {
        const float mo = __shfl_xor(m[i], 32);
        float f = fmaxf(wown * m[i] + woth * mo, 0.f);
        fused[i] = f;
        sum += f;
        sq  += f * f;
    }
    #pragma unroll
    for (int off = 1; off <= 32; off <<= 1) {
        sum += __shfl_xor(sum, off);
        sq  += __shfl_xor(sq,  off);
    }
    // both halves hold duplicates -> totals are 2x
    const float mu  = sum * (0.5f / ODIM);
    const float var = sq  * (0.5f / ODIM) - mu * mu;
    const float rinv = rsqrtf(var + 1e-5f);

    if (p == 0) {
        float4 g0 = *(const float4*)&gamma[c];
        float4 g1 = *(const float4*)&gamma[c + 4];
        float4 b0 = *(const float4*)&beta[c];
        float4 b1 = *(const float4*)&beta[c + 4];
        float gv[8] = {g0.x, g0.y, g0.z, g0.w, g1.x, g1.y, g1.z, g1.w};
        float bv[8] = {b0.x, b0.y, b0.z, b0.w, b1.x, b1.y, b1.z, b1.w};
        float o[8];
        #pragma unroll
        for (int i = 0; i < 8; ++i) o[i] = (fused[i] - mu) * rinv * gv[i] + bv[i];
        float4 o0, o1;
        o0.x = o[0]; o0.y = o[1]; o0.z = o[2]; o0.w = o[3];
        o1.x = o[4]; o1.y = o[5]; o1.z = o[6]; o1.w = o[7];
        *(float4*)&out[(size_t)row * ODIM + c]     = o0;
        *(float4*)&out[(size_t)row * ODIM + c + 4] = o1;
    }
}

// ---------------------------------------------------------------------------
extern "C" void kernel_launch(void* const* d_in, const int* in_sizes, int n_in,
                              void* d_out, int out_size, void* d_ws, size_t ws_size,
                              hipStream_t stream)
{
    const float* xB   = (const float*)d_in[1];
    const int*   ei0  = (const int*)d_in[2];
    const int*   ei1  = (const int*)d_in[3];
    const float* W0   = (const float*)d_in[4];
    const float* b0   = (const float*)d_in[5];
    const float* W1   = (const float*)d_in[6];
    const float* b1   = (const float*)d_in[7];
    const float* sem  = (const float*)d_in[8];
    const float* gam  = (const float*)d_in[9];
    const float* bet  = (const float*)d_in[10];

    float* out = (float*)d_out;

    // workspace: projf only (204.8 MB) — matches R2's proven footprint
    float* projf = (float*)d_ws;

    // All small scratch lives in the out_B half of d_out (zeroed at the end).
    // CSR (~5 MB) + split W (0.5 MB) + biases.
    u32* cnt    = (u32*)(out + (size_t)NA * ODIM);
    u32* offs   = cnt    + 200064;
    u32* parts  = offs   + 200128;
    u32* cursor = parts  + 1024;
    int* elist  = (int*)(cursor + 200064);          // 640000 ints
    __bf16* Wth = (__bf16*)(elist + 640000);        // 512*256 bf16
    __bf16* Wtl = Wth + (size_t)512 * KDIM;         // 512*256 bf16
    float*  bcat = (float*)(Wtl + (size_t)512 * KDIM);  // 512 f32

    // 1) split W -> bf16 hi/lo (tiny)
    convert_w<<<64, 256, 0, stream>>>(W0, b0, W1, b1, Wth, Wtl, bcat);

    // 2) split-bf16 MFMA projection GEMM -> projf (f32)
    dim3 ggrid(NCAT / 128, (NB + 127) / 128);
    proj_gemm<<<ggrid, 256, 0, stream>>>(xB, Wth, Wtl, bcat, projf);

    // 3) CSR build
    hipMemsetAsync(cnt, 0, (size_t)NBUCK * sizeof(u32), stream);
    const int egrid = (2 * NEDGE + 255) / 256;
    csr_count<<<egrid, 256, 0, stream>>>(ei0, ei1, cnt);
    scan1<<<NPART, 256, 0, stream>>>(cnt, offs, parts);
    scan2<<<1, 1024, 0, stream>>>(parts);
    scan3<<<NPART, 256, 0, stream>>>(offs, parts, cursor);
    csr_fill<<<egrid, 256, 0, stream>>>(ei0, ei1, cursor, elist);

    // 4) fused gather + epilogue
    gather_finalize<<<(NA + 3) / 4, 256, 0, stream>>>(projf, offs, elist, out,
                                                      sem, gam, bet);

    // 5) out_B half must be zeros (also wipes all scratch)
    hipMemsetAsync(out + (size_t)NA * ODIM, 0,
                   (size_t)NA * ODIM * sizeof(float), stream);
}